// Round 1
// baseline (353.529 us; speedup 1.0000x reference)
//
#include <hip/hip_runtime.h>
#include <math.h>

#define NDIM 128

// ---------------- fused q/k/v projection GEMM ----------------
// out[r][j] = sum_i z[r][i] * W[i][j] + b[j]
// block: 128 threads (thread = output column j), 16 rows per block.
__global__ __launch_bounds__(128) void qkv_gemm(
    const float* __restrict__ z,
    const float* __restrict__ Wq, const float* __restrict__ bq,
    const float* __restrict__ Wk, const float* __restrict__ bk,
    const float* __restrict__ Wv, const float* __restrict__ bv,
    float* __restrict__ q, float* __restrict__ k, float* __restrict__ v,
    int n) {
  const int ROWS = 16;
  __shared__ float zt[ROWS][NDIM];
  int t = threadIdx.x;            // 0..127 = output column
  int r0 = blockIdx.x * ROWS;
  for (int r = 0; r < ROWS; ++r) {
    int row = r0 + r;
    zt[r][t] = (row < n) ? z[(size_t)row * NDIM + t] : 0.f;
  }
  __syncthreads();
  float aq[ROWS], ak[ROWS], av[ROWS];
#pragma unroll
  for (int r = 0; r < ROWS; ++r) { aq[r] = 0.f; ak[r] = 0.f; av[r] = 0.f; }
  for (int i = 0; i < NDIM; ++i) {
    float wq = Wq[i * NDIM + t];
    float wk = Wk[i * NDIM + t];
    float wv = Wv[i * NDIM + t];
#pragma unroll
    for (int r = 0; r < ROWS; ++r) {
      float zv = zt[r][i];
      aq[r] = fmaf(zv, wq, aq[r]);
      ak[r] = fmaf(zv, wk, ak[r]);
      av[r] = fmaf(zv, wv, av[r]);
    }
  }
  float bqv = bq[t], bkv = bk[t], bvv = bv[t];
  for (int r = 0; r < ROWS; ++r) {
    int row = r0 + r;
    if (row < n) {
      q[(size_t)row * NDIM + t] = aq[r] + bqv;
      k[(size_t)row * NDIM + t] = ak[r] + bkv;
      v[(size_t)row * NDIM + t] = av[r] + bvv;
    }
  }
}

// ---------------- degree histogram ----------------
__global__ void hist_kernel(const int* __restrict__ dst, int* __restrict__ counts,
                            int ne) {
  int e = blockIdx.x * blockDim.x + threadIdx.x;
  if (e < ne) atomicAdd(&counts[dst[e]], 1);
}

// ---------------- exclusive scan of counts -> offsets (single block) ----------------
__global__ __launch_bounds__(1024) void scan_kernel(const int* __restrict__ counts,
                                                    int* __restrict__ offsets, int n) {
  __shared__ int wsum[16];
  __shared__ int wpre[16];
  int tid = threadIdx.x, lane = tid & 63, wid = tid >> 6;
  int carry = 0;
  for (int base = 0; base < n; base += 1024) {
    int i = base + tid;
    int x = (i < n) ? counts[i] : 0;
    int incl = x;
#pragma unroll
    for (int off = 1; off < 64; off <<= 1) {
      int tmp = __shfl_up(incl, off);
      if (lane >= off) incl += tmp;
    }
    if (lane == 63) wsum[wid] = incl;
    __syncthreads();
    if (wid == 0) {
      int s = (lane < 16) ? wsum[lane] : 0;
#pragma unroll
      for (int off = 1; off < 16; off <<= 1) {
        int tmp = __shfl_up(s, off);
        if (lane >= off) s += tmp;
      }
      if (lane < 16) wpre[lane] = s;
    }
    __syncthreads();
    int wexcl = (wid == 0) ? 0 : wpre[wid - 1];
    if (i < n) offsets[i] = carry + wexcl + (incl - x);
    carry += wpre[15];
    __syncthreads();
  }
}

// ---------------- scatter edges sorted by dst ----------------
__global__ void scatter_kernel(const int* __restrict__ src, const int* __restrict__ dst,
                               const int* __restrict__ offsets, int* __restrict__ cursor,
                               int* __restrict__ sorted_src, int ne) {
  int e = blockIdx.x * blockDim.x + threadIdx.x;
  if (e < ne) {
    int d = dst[e];
    int pos = offsets[d] + atomicAdd(&cursor[d], 1);
    sorted_src[pos] = src[e];
  }
}

// ---------------- per-node attention aggregate (one wave per node) ----------------
__global__ __launch_bounds__(256) void agg_kernel(
    const float* __restrict__ q, const float* __restrict__ k, const float* __restrict__ v,
    const int* __restrict__ offsets, const int* __restrict__ counts,
    const int* __restrict__ sorted_src, float* __restrict__ out, int n) {
  int lane = threadIdx.x & 63;
  int node = blockIdx.x * 4 + (threadIdx.x >> 6);
  if (node >= n) return;
  const float tau = 0.08838834764831845f;  // 1/sqrt(128)
  int beg = offsets[node];
  int deg = counts[node];
  float q0 = q[(size_t)node * NDIM + lane];
  float q1 = q[(size_t)node * NDIM + 64 + lane];
  float m = -INFINITY, sumex = 0.f, h0 = 0.f, h1 = 0.f;
  for (int cb = 0; cb < deg; cb += 64) {
    int cnt = min(64, deg - cb);
    int s = (lane < cnt) ? sorted_src[beg + cb + lane] : 0;
    float evec = -INFINITY;
    for (int j = 0; j < cnt; ++j) {
      int sj = __shfl(s, j);
      const float* krow = k + (size_t)sj * NDIM;
      float p = krow[lane] * q0 + krow[64 + lane] * q1;
#pragma unroll
      for (int o = 32; o > 0; o >>= 1) p += __shfl_xor(p, o);
      if (lane == j) evec = p * tau;
    }
    float cm = evec;
#pragma unroll
    for (int o = 32; o > 0; o >>= 1) cm = fmaxf(cm, __shfl_xor(cm, o));
    float new_m = fmaxf(m, cm);
    float scale = __expf(m - new_m);  // exp(-inf)=0 on first chunk; h,sumex are 0 anyway
    float ex = (lane < cnt) ? __expf(evec - new_m) : 0.f;
    float se = ex;
#pragma unroll
    for (int o = 32; o > 0; o >>= 1) se += __shfl_xor(se, o);
    sumex = sumex * scale + se;
    h0 *= scale;
    h1 *= scale;
    for (int j = 0; j < cnt; ++j) {
      float w = __shfl(ex, j);
      int sj = __shfl(s, j);
      const float* vrow = v + (size_t)sj * NDIM;
      h0 = fmaf(w, vrow[lane], h0);
      h1 = fmaf(w, vrow[64 + lane], h1);
    }
    m = new_m;
  }
  float denom = (sumex > 0.f) ? sumex : 1.f;
  out[(size_t)node * NDIM + lane] = h0 / denom;
  out[(size_t)node * NDIM + 64 + lane] = h1 / denom;
}

extern "C" void kernel_launch(void* const* d_in, const int* in_sizes, int n_in,
                              void* d_out, int out_size, void* d_ws, size_t ws_size,
                              hipStream_t stream) {
  const float* z  = (const float*)d_in[0];
  const float* Wq = (const float*)d_in[1];
  const float* bq = (const float*)d_in[2];
  const float* Wk = (const float*)d_in[3];
  const float* bk = (const float*)d_in[4];
  const float* Wv = (const float*)d_in[5];
  const float* bv = (const float*)d_in[6];
  const int* src  = (const int*)d_in[7];
  const int* dst  = (const int*)d_in[8];
  int n  = in_sizes[0] / NDIM;  // 50000
  int ne = in_sizes[7];         // 800000
  float* out = (float*)d_out;

  char* ws = (char*)d_ws;
  size_t szqkv = (size_t)n * NDIM * sizeof(float);          // 25.6 MB
  size_t nb = (((size_t)n * sizeof(int)) + 255) & ~(size_t)255;  // aligned 200 KB
  float* q = (float*)(ws);
  float* k = (float*)(ws + szqkv);
  float* v = (float*)(ws + 2 * szqkv);
  int* counts     = (int*)(ws + 3 * szqkv);
  int* cursor     = (int*)(ws + 3 * szqkv + nb);
  int* offsets    = (int*)(ws + 3 * szqkv + 2 * nb);
  int* sorted_src = (int*)(ws + 3 * szqkv + 3 * nb);

  // 1) projections
  qkv_gemm<<<(n + 15) / 16, 128, 0, stream>>>(z, Wq, bq, Wk, bk, Wv, bv, q, k, v, n);
  // 2) zero counters (counts + cursor are adjacent)
  hipMemsetAsync(counts, 0, 2 * nb, stream);
  // 3) degree histogram
  hist_kernel<<<(ne + 255) / 256, 256, 0, stream>>>(dst, counts, ne);
  // 4) exclusive scan
  scan_kernel<<<1, 1024, 0, stream>>>(counts, offsets, n);
  // 5) counting-sort scatter
  scatter_kernel<<<(ne + 255) / 256, 256, 0, stream>>>(src, dst, offsets, cursor,
                                                       sorted_src, ne);
  // 6) per-node softmax-aggregate
  agg_kernel<<<(n + 3) / 4, 256, 0, stream>>>(q, k, v, offsets, counts, sorted_src,
                                              out, n);
}

// Round 2
// 281.116 us; speedup vs baseline: 1.2576x; 1.2576x over previous
//
#include <hip/hip_runtime.h>
#include <math.h>

#define NDIM 128

// ---------------- fused q/k/v projection GEMM ----------------
// out[r][j] = sum_i z[r][i] * W[i][j] + b[j]
// block: 128 threads (thread = output column j), 16 rows per block.
__global__ __launch_bounds__(128) void qkv_gemm(
    const float* __restrict__ z,
    const float* __restrict__ Wq, const float* __restrict__ bq,
    const float* __restrict__ Wk, const float* __restrict__ bk,
    const float* __restrict__ Wv, const float* __restrict__ bv,
    float* __restrict__ q, float* __restrict__ k, float* __restrict__ v,
    int n) {
  const int ROWS = 16;
  __shared__ float4 zt[ROWS][NDIM / 4];  // 8 KB
  int t = threadIdx.x;                   // 0..127 = output column
  int r0 = blockIdx.x * ROWS;
  const float4* z4 = (const float4*)z;
#pragma unroll
  for (int it = 0; it < 4; ++it) {
    int idx = it * 128 + t;  // 0..511
    int r = idx >> 5, c = idx & 31;
    int row = r0 + r;
    float4 val = make_float4(0.f, 0.f, 0.f, 0.f);
    if (row < n) val = z4[(size_t)row * 32 + c];
    zt[r][c] = val;
  }
  __syncthreads();
  float aq[ROWS], ak[ROWS], av[ROWS];
#pragma unroll
  for (int r = 0; r < ROWS; ++r) { aq[r] = 0.f; ak[r] = 0.f; av[r] = 0.f; }
  for (int i4 = 0; i4 < 32; ++i4) {
    int i = i4 * 4;
    float wq0 = Wq[(i + 0) * NDIM + t], wq1 = Wq[(i + 1) * NDIM + t];
    float wq2 = Wq[(i + 2) * NDIM + t], wq3 = Wq[(i + 3) * NDIM + t];
    float wk0 = Wk[(i + 0) * NDIM + t], wk1 = Wk[(i + 1) * NDIM + t];
    float wk2 = Wk[(i + 2) * NDIM + t], wk3 = Wk[(i + 3) * NDIM + t];
    float wv0 = Wv[(i + 0) * NDIM + t], wv1 = Wv[(i + 1) * NDIM + t];
    float wv2 = Wv[(i + 2) * NDIM + t], wv3 = Wv[(i + 3) * NDIM + t];
#pragma unroll
    for (int r = 0; r < ROWS; ++r) {
      float4 zv = zt[r][i4];  // wave-uniform broadcast b128
      float a;
      a = aq[r];
      a = fmaf(zv.x, wq0, a); a = fmaf(zv.y, wq1, a);
      a = fmaf(zv.z, wq2, a); a = fmaf(zv.w, wq3, a);
      aq[r] = a;
      a = ak[r];
      a = fmaf(zv.x, wk0, a); a = fmaf(zv.y, wk1, a);
      a = fmaf(zv.z, wk2, a); a = fmaf(zv.w, wk3, a);
      ak[r] = a;
      a = av[r];
      a = fmaf(zv.x, wv0, a); a = fmaf(zv.y, wv1, a);
      a = fmaf(zv.z, wv2, a); a = fmaf(zv.w, wv3, a);
      av[r] = a;
    }
  }
  float bqv = bq[t], bkv = bk[t], bvv = bv[t];
  for (int r = 0; r < ROWS; ++r) {
    int row = r0 + r;
    if (row < n) {
      q[(size_t)row * NDIM + t] = aq[r] + bqv;
      k[(size_t)row * NDIM + t] = ak[r] + bkv;
      v[(size_t)row * NDIM + t] = av[r] + bvv;
    }
  }
}

// ---------------- degree histogram ----------------
__global__ void hist_kernel(const int* __restrict__ dst, int* __restrict__ counts,
                            int ne) {
  int e = blockIdx.x * blockDim.x + threadIdx.x;
  if (e < ne) atomicAdd(&counts[dst[e]], 1);
}

// ---------------- multi-block exclusive scan ----------------
__global__ __launch_bounds__(256) void scan_blocks(const int* __restrict__ counts,
                                                   int* __restrict__ offs,
                                                   int* __restrict__ bsums, int n) {
  __shared__ int ws[4];
  int tid = threadIdx.x, lane = tid & 63, wid = tid >> 6;
  int i = blockIdx.x * 256 + tid;
  int x = (i < n) ? counts[i] : 0;
  int incl = x;
#pragma unroll
  for (int off = 1; off < 64; off <<= 1) {
    int tmp = __shfl_up(incl, off);
    if (lane >= off) incl += tmp;
  }
  if (lane == 63) ws[wid] = incl;
  __syncthreads();
  int add = 0;
#pragma unroll
  for (int w = 0; w < 4; ++w)
    if (w < wid) add += ws[w];
  if (i < n) offs[i] = add + incl - x;  // exclusive within block
  if (tid == 255) bsums[blockIdx.x] = add + incl;
}

__global__ __launch_bounds__(256) void scan_tops(int* __restrict__ bsums, int nb) {
  __shared__ int ws[4];
  int tid = threadIdx.x, lane = tid & 63, wid = tid >> 6;
  int x = (tid < nb) ? bsums[tid] : 0;
  int incl = x;
#pragma unroll
  for (int off = 1; off < 64; off <<= 1) {
    int tmp = __shfl_up(incl, off);
    if (lane >= off) incl += tmp;
  }
  if (lane == 63) ws[wid] = incl;
  __syncthreads();
  int add = 0;
#pragma unroll
  for (int w = 0; w < 4; ++w)
    if (w < wid) add += ws[w];
  if (tid < nb) bsums[tid] = add + incl - x;  // exclusive, in place
}

__global__ void scan_add(int* __restrict__ offs, const int* __restrict__ bsums,
                         int n) {
  int i = blockIdx.x * 256 + threadIdx.x;
  if (i < n) offs[i] += bsums[blockIdx.x];
}

// ---------------- scatter edges sorted by dst ----------------
__global__ void scatter_kernel(const int* __restrict__ src, const int* __restrict__ dst,
                               const int* __restrict__ offsets, int* __restrict__ cursor,
                               int* __restrict__ sorted_src, int ne) {
  int e = blockIdx.x * blockDim.x + threadIdx.x;
  if (e < ne) {
    int d = dst[e];
    int pos = offsets[d] + atomicAdd(&cursor[d], 1);
    sorted_src[pos] = src[e];
  }
}

// ---------------- per-node attention aggregate ----------------
// 1 wave per node, 4 waves/block. Within a wave: 4 groups of 16 lanes,
// each group processes one edge at a time (4 edges in flight).
__global__ __launch_bounds__(256) void agg_kernel(
    const float* __restrict__ q, const float* __restrict__ k, const float* __restrict__ v,
    const int* __restrict__ offsets, const int* __restrict__ counts,
    const int* __restrict__ sorted_src, float* __restrict__ out, int n) {
  int lane = threadIdx.x & 63;
  int node = blockIdx.x * 4 + (threadIdx.x >> 6);
  if (node >= n) return;
  const float tau = 0.08838834764831845f;  // 1/sqrt(128)
  int gl = lane & 15;   // lane within group
  int grp = lane >> 4;  // group 0..3
  int beg = offsets[node];
  int deg = counts[node];
  // q row: lane holds dims gl*8 .. gl*8+7
  const float4* q4 = (const float4*)(q + (size_t)node * NDIM);
  float4 qa = q4[gl * 2], qb = q4[gl * 2 + 1];
  float m = -INFINITY, sumex = 0.f;
  float hp[8];
#pragma unroll
  for (int i = 0; i < 8; ++i) hp[i] = 0.f;
  for (int cb = 0; cb < deg; cb += 64) {
    int cnt = min(64, deg - cb);
    int sj = (lane < cnt) ? sorted_src[beg + cb + lane] : -1;
    float evec = -INFINITY;
    int nsub = (cnt + 3) >> 2;
    // ---- logits: 4 edges in parallel (one per 16-lane group) ----
    for (int s = 0; s < nsub; ++s) {
      int j = (s << 2) | grp;
      int row = __shfl(sj, j);
      float part = 0.f;
      if (row >= 0) {
        const float4* kr = (const float4*)(k + (size_t)row * NDIM);
        float4 ka = kr[gl * 2], kb = kr[gl * 2 + 1];
        part = qa.x * ka.x + qa.y * ka.y + qa.z * ka.z + qa.w * ka.w +
               qb.x * kb.x + qb.y * kb.y + qb.z * kb.z + qb.w * kb.w;
      }
      part += __shfl_xor(part, 1);
      part += __shfl_xor(part, 2);
      part += __shfl_xor(part, 4);
      part += __shfl_xor(part, 8);
      // deliver e_j to lane j (lane j needs group (lane&3)'s value)
      float r = __shfl(part, (lane & 3) << 4);
      if ((lane >> 2) == s && lane < cnt) evec = r * tau;
    }
    // ---- online softmax across the wave ----
    float cm = evec;
#pragma unroll
    for (int o = 32; o > 0; o >>= 1) cm = fmaxf(cm, __shfl_xor(cm, o));
    float new_m = fmaxf(m, cm);
    float scale = __expf(m - new_m);  // exp(-inf)=0 first chunk; hp,sumex are 0
    float ex = (lane < cnt) ? __expf(evec - new_m) : 0.f;
    float se = ex;
#pragma unroll
    for (int o = 32; o > 0; o >>= 1) se += __shfl_xor(se, o);
    sumex = sumex * scale + se;
#pragma unroll
    for (int i = 0; i < 8; ++i) hp[i] *= scale;
    // ---- weighted V accumulation: 4 edges in parallel ----
    for (int s = 0; s < nsub; ++s) {
      int j = (s << 2) | grp;
      int row = __shfl(sj, j);
      float w = __shfl(ex, j);
      if (row >= 0) {
        const float4* vr = (const float4*)(v + (size_t)row * NDIM);
        float4 va = vr[gl * 2], vb = vr[gl * 2 + 1];
        hp[0] = fmaf(w, va.x, hp[0]);
        hp[1] = fmaf(w, va.y, hp[1]);
        hp[2] = fmaf(w, va.z, hp[2]);
        hp[3] = fmaf(w, va.w, hp[3]);
        hp[4] = fmaf(w, vb.x, hp[4]);
        hp[5] = fmaf(w, vb.y, hp[5]);
        hp[6] = fmaf(w, vb.z, hp[6]);
        hp[7] = fmaf(w, vb.w, hp[7]);
      }
    }
    m = new_m;
  }
  // cross-group reduce (groups hold partial sums over edge subsets)
#pragma unroll
  for (int i = 0; i < 8; ++i) {
    hp[i] += __shfl_xor(hp[i], 16);
    hp[i] += __shfl_xor(hp[i], 32);
  }
  if (grp == 0) {
    float denom = (sumex > 0.f) ? sumex : 1.f;
    float inv = 1.f / denom;
    float4* o4 = (float4*)(out + (size_t)node * NDIM);
    o4[gl * 2] = make_float4(hp[0] * inv, hp[1] * inv, hp[2] * inv, hp[3] * inv);
    o4[gl * 2 + 1] = make_float4(hp[4] * inv, hp[5] * inv, hp[6] * inv, hp[7] * inv);
  }
}

extern "C" void kernel_launch(void* const* d_in, const int* in_sizes, int n_in,
                              void* d_out, int out_size, void* d_ws, size_t ws_size,
                              hipStream_t stream) {
  const float* z  = (const float*)d_in[0];
  const float* Wq = (const float*)d_in[1];
  const float* bq = (const float*)d_in[2];
  const float* Wk = (const float*)d_in[3];
  const float* bk = (const float*)d_in[4];
  const float* Wv = (const float*)d_in[5];
  const float* bv = (const float*)d_in[6];
  const int* src  = (const int*)d_in[7];
  const int* dst  = (const int*)d_in[8];
  int n  = in_sizes[0] / NDIM;  // 50000
  int ne = in_sizes[7];         // 800000
  float* out = (float*)d_out;

  char* ws = (char*)d_ws;
  size_t szqkv = (size_t)n * NDIM * sizeof(float);               // 25.6 MB
  size_t nb = (((size_t)n * sizeof(int)) + 255) & ~(size_t)255;  // aligned 200 KB
  float* q = (float*)(ws);
  float* k = (float*)(ws + szqkv);
  float* v = (float*)(ws + 2 * szqkv);
  int* counts     = (int*)(ws + 3 * szqkv);
  int* cursor     = (int*)(ws + 3 * szqkv + nb);  // also reused as bsums buffer
  int* offsets    = (int*)(ws + 3 * szqkv + 2 * nb);
  int* sorted_src = (int*)(ws + 3 * szqkv + 3 * nb);

  int nblk = (n + 255) / 256;  // 196 (<= 256 required by scan_tops)

  // 1) projections
  qkv_gemm<<<(n + 15) / 16, 128, 0, stream>>>(z, Wq, bq, Wk, bk, Wv, bv, q, k, v, n);
  // 2) zero degree counters
  hipMemsetAsync(counts, 0, nb, stream);
  // 3) degree histogram
  hist_kernel<<<(ne + 255) / 256, 256, 0, stream>>>(dst, counts, ne);
  // 4) multi-block exclusive scan (bsums overlaid on cursor buffer)
  scan_blocks<<<nblk, 256, 0, stream>>>(counts, offsets, cursor, n);
  scan_tops<<<1, 256, 0, stream>>>(cursor, nblk);
  scan_add<<<nblk, 256, 0, stream>>>(offsets, cursor, n);
  // 5) re-zero cursor, then counting-sort scatter
  hipMemsetAsync(cursor, 0, nb, stream);
  scatter_kernel<<<(ne + 255) / 256, 256, 0, stream>>>(src, dst, offsets, cursor,
                                                       sorted_src, ne);
  // 6) per-node softmax-aggregate
  agg_kernel<<<(n + 3) / 4, 256, 0, stream>>>(q, k, v, offsets, counts, sorted_src,
                                              out, n);
}

// Round 3
// 226.063 us; speedup vs baseline: 1.5639x; 1.2435x over previous
//
#include <hip/hip_runtime.h>
#include <math.h>

#define NDIM 128

typedef __attribute__((ext_vector_type(8))) short short8v;
typedef __attribute__((ext_vector_type(4))) float f32x4;

__device__ inline unsigned short f2bf(float f) {
  unsigned u = __float_as_uint(f);
  unsigned r = (u + 0x7fff + ((u >> 16) & 1)) >> 16;  // RNE
  return (unsigned short)r;
}

// ---------------- z -> bf16 conversion (streaming) ----------------
__global__ __launch_bounds__(256) void zconv_kernel(const float* __restrict__ z,
                                                    ushort* __restrict__ zb,
                                                    size_t total) {
  size_t base = ((size_t)blockIdx.x * 256 + threadIdx.x) * 8;
  if (base >= total) return;
  const float4* z4 = (const float4*)(z + base);
  float4 a = z4[0], b = z4[1];
  uint4 o;
  o.x = (unsigned)f2bf(a.x) | ((unsigned)f2bf(a.y) << 16);
  o.y = (unsigned)f2bf(a.z) | ((unsigned)f2bf(a.w) << 16);
  o.z = (unsigned)f2bf(b.x) | ((unsigned)f2bf(b.y) << 16);
  o.w = (unsigned)f2bf(b.z) | ((unsigned)f2bf(b.w) << 16);
  *(uint4*)(zb + base) = o;
}

// ---------------- W transpose + bf16 convert: wt[mat][ncol][k] ----------------
__global__ __launch_bounds__(256) void wprep_kernel(const float* __restrict__ Wq,
                                                    const float* __restrict__ Wk,
                                                    const float* __restrict__ Wv,
                                                    ushort* __restrict__ wt) {
  int tid = blockIdx.x * 256 + threadIdx.x;
  if (tid >= 3 * NDIM * NDIM) return;
  int mat = tid >> 14;
  int idx = tid & 16383;
  int nn = idx >> 7;   // output col
  int kk = idx & 127;  // input dim
  const float* W = (mat == 0) ? Wq : (mat == 1) ? Wk : Wv;
  wt[tid] = f2bf(W[kk * NDIM + nn]);
}

// ---------------- q/k/v projection via bf16 MFMA ----------------
// block = 256 threads (4 waves), 64 rows/block (16 rows/wave), N=128 full.
// A frag (16x16x32): lane holds z[row0+(l&15)][kk*32+(l>>4)*8 ..+7]
// B frag:            lane holds Wt[mat][nt*16+(l&15)][kk*32+(l>>4)*8 ..+7]
// C/D: col = lane&15, row = (lane>>4)*4 + reg   [guide §3, m89-verified]
__global__ __launch_bounds__(256) void qkv_mfma(
    const ushort* __restrict__ zb, const ushort* __restrict__ wt,
    const float* __restrict__ bq, const float* __restrict__ bk,
    const float* __restrict__ bv,
    float* __restrict__ q, ushort* __restrict__ kb, ushort* __restrict__ vb,
    int n) {
  int lane = threadIdx.x & 63;
  int w = threadIdx.x >> 6;
  int l15 = lane & 15, kgrp = lane >> 4;
  int row_a = blockIdx.x * 64 + w * 16 + l15;
  bool arow_ok = row_a < n;
  const short8v* zrow = (const short8v*)(zb + (size_t)row_a * NDIM);
  short8v afr[4];
#pragma unroll
  for (int kk = 0; kk < 4; ++kk) {
    short8v av = (short8v)0;
    if (arow_ok) av = zrow[kk * 4 + kgrp];
    afr[kk] = av;
  }
  int orow_base = blockIdx.x * 64 + w * 16 + kgrp * 4;
#pragma unroll
  for (int mat = 0; mat < 3; ++mat) {
    const short8v* wrow = (const short8v*)(wt + (size_t)mat * NDIM * NDIM);
    const float* bias = (mat == 0) ? bq : (mat == 1) ? bk : bv;
    f32x4 acc[8];
#pragma unroll
    for (int nt = 0; nt < 8; ++nt) acc[nt] = (f32x4)0.f;
#pragma unroll
    for (int kk = 0; kk < 4; ++kk) {
#pragma unroll
      for (int nt = 0; nt < 8; ++nt) {
        short8v bfr = wrow[(nt * 16 + l15) * 16 + kk * 4 + kgrp];
        acc[nt] = __builtin_amdgcn_mfma_f32_16x16x32_bf16(afr[kk], bfr, acc[nt],
                                                          0, 0, 0);
      }
    }
#pragma unroll
    for (int nt = 0; nt < 8; ++nt) {
      int c = nt * 16 + l15;
      float bv_ = bias[c];
#pragma unroll
      for (int i = 0; i < 4; ++i) {
        int r = orow_base + i;
        if (r < n) {
          float val = acc[nt][i] + bv_;
          if (mat == 0) q[(size_t)r * NDIM + c] = val;
          else if (mat == 1) kb[(size_t)r * NDIM + c] = f2bf(val);
          else vb[(size_t)r * NDIM + c] = f2bf(val);
        }
      }
    }
  }
}

// ---------------- degree histogram ----------------
__global__ void hist_kernel(const int* __restrict__ dst, int* __restrict__ counts,
                            int ne) {
  int e = blockIdx.x * blockDim.x + threadIdx.x;
  if (e < ne) atomicAdd(&counts[dst[e]], 1);
}

// ---------------- multi-block exclusive scan ----------------
__global__ __launch_bounds__(256) void scan_blocks(const int* __restrict__ counts,
                                                   int* __restrict__ offs,
                                                   int* __restrict__ bsums, int n) {
  __shared__ int ws[4];
  int tid = threadIdx.x, lane = tid & 63, wid = tid >> 6;
  int i = blockIdx.x * 256 + tid;
  int x = (i < n) ? counts[i] : 0;
  int incl = x;
#pragma unroll
  for (int off = 1; off < 64; off <<= 1) {
    int tmp = __shfl_up(incl, off);
    if (lane >= off) incl += tmp;
  }
  if (lane == 63) ws[wid] = incl;
  __syncthreads();
  int add = 0;
#pragma unroll
  for (int w = 0; w < 4; ++w)
    if (w < wid) add += ws[w];
  if (i < n) offs[i] = add + incl - x;
  if (tid == 255) bsums[blockIdx.x] = add + incl;
}

__global__ __launch_bounds__(256) void scan_tops(int* __restrict__ bsums, int nb) {
  __shared__ int ws[4];
  int tid = threadIdx.x, lane = tid & 63, wid = tid >> 6;
  int x = (tid < nb) ? bsums[tid] : 0;
  int incl = x;
#pragma unroll
  for (int off = 1; off < 64; off <<= 1) {
    int tmp = __shfl_up(incl, off);
    if (lane >= off) incl += tmp;
  }
  if (lane == 63) ws[wid] = incl;
  __syncthreads();
  int add = 0;
#pragma unroll
  for (int w = 0; w < 4; ++w)
    if (w < wid) add += ws[w];
  if (tid < nb) bsums[tid] = add + incl - x;
}

__global__ void scan_add(int* __restrict__ offs, const int* __restrict__ bsums,
                         int n) {
  int i = blockIdx.x * 256 + threadIdx.x;
  if (i < n) offs[i] += bsums[blockIdx.x];
}

// ---------------- scatter edges sorted by dst ----------------
__global__ void scatter_kernel(const int* __restrict__ src, const int* __restrict__ dst,
                               const int* __restrict__ offsets, int* __restrict__ cursor,
                               int* __restrict__ sorted_src, int ne) {
  int e = blockIdx.x * blockDim.x + threadIdx.x;
  if (e < ne) {
    int d = dst[e];
    int pos = offsets[d] + atomicAdd(&cursor[d], 1);
    sorted_src[pos] = src[e];
  }
}

// ---------------- per-node attention aggregate ----------------
// 1 wave per node; 4 groups of 16 lanes each own one edge (4 in flight).
// k/v gathered as bf16 rows (256 B), q in f32.
__global__ __launch_bounds__(256) void agg_kernel(
    const float* __restrict__ q, const ushort* __restrict__ kb,
    const ushort* __restrict__ vb,
    const int* __restrict__ offsets, const int* __restrict__ counts,
    const int* __restrict__ sorted_src, float* __restrict__ out, int n) {
  int lane = threadIdx.x & 63;
  int node = blockIdx.x * 4 + (threadIdx.x >> 6);
  if (node >= n) return;
  const float tau = 0.08838834764831845f;  // 1/sqrt(128)
  int gl = lane & 15;
  int grp = lane >> 4;
  int beg = offsets[node];
  int deg = counts[node];
  const float4* q4 = (const float4*)(q + (size_t)node * NDIM);
  float4 qa = q4[gl * 2], qb = q4[gl * 2 + 1];
  float m = -INFINITY, sumex = 0.f;
  float hp[8];
#pragma unroll
  for (int i = 0; i < 8; ++i) hp[i] = 0.f;
  for (int cb = 0; cb < deg; cb += 64) {
    int cnt = min(64, deg - cb);
    int sj = (lane < cnt) ? sorted_src[beg + cb + lane] : -1;
    float evec = -INFINITY;
    int nsub = (cnt + 3) >> 2;
    // ---- logits: 4 edges in parallel ----
    for (int s = 0; s < nsub; ++s) {
      int j = (s << 2) | grp;
      int row = __shfl(sj, j);
      float part = 0.f;
      if (row >= 0) {
        uint4 kv = ((const uint4*)(kb + (size_t)row * NDIM))[gl];
        float f0 = __uint_as_float(kv.x << 16), f1 = __uint_as_float(kv.x & 0xffff0000u);
        float f2 = __uint_as_float(kv.y << 16), f3 = __uint_as_float(kv.y & 0xffff0000u);
        float f4 = __uint_as_float(kv.z << 16), f5 = __uint_as_float(kv.z & 0xffff0000u);
        float f6 = __uint_as_float(kv.w << 16), f7 = __uint_as_float(kv.w & 0xffff0000u);
        part = qa.x * f0 + qa.y * f1 + qa.z * f2 + qa.w * f3 +
               qb.x * f4 + qb.y * f5 + qb.z * f6 + qb.w * f7;
      }
      part += __shfl_xor(part, 1);
      part += __shfl_xor(part, 2);
      part += __shfl_xor(part, 4);
      part += __shfl_xor(part, 8);
      float r = __shfl(part, (lane & 3) << 4);
      if ((lane >> 2) == s && lane < cnt) evec = r * tau;
    }
    // ---- online softmax ----
    float cm = evec;
#pragma unroll
    for (int o = 32; o > 0; o >>= 1) cm = fmaxf(cm, __shfl_xor(cm, o));
    float new_m = fmaxf(m, cm);
    float scale = __expf(m - new_m);
    float ex = (lane < cnt) ? __expf(evec - new_m) : 0.f;
    float se = ex;
#pragma unroll
    for (int o = 32; o > 0; o >>= 1) se += __shfl_xor(se, o);
    sumex = sumex * scale + se;
#pragma unroll
    for (int i = 0; i < 8; ++i) hp[i] *= scale;
    // ---- weighted V accumulation: 4 edges in parallel ----
    for (int s = 0; s < nsub; ++s) {
      int j = (s << 2) | grp;
      int row = __shfl(sj, j);
      float ww = __shfl(ex, j);
      if (row >= 0) {
        uint4 vv = ((const uint4*)(vb + (size_t)row * NDIM))[gl];
        hp[0] = fmaf(ww, __uint_as_float(vv.x << 16), hp[0]);
        hp[1] = fmaf(ww, __uint_as_float(vv.x & 0xffff0000u), hp[1]);
        hp[2] = fmaf(ww, __uint_as_float(vv.y << 16), hp[2]);
        hp[3] = fmaf(ww, __uint_as_float(vv.y & 0xffff0000u), hp[3]);
        hp[4] = fmaf(ww, __uint_as_float(vv.z << 16), hp[4]);
        hp[5] = fmaf(ww, __uint_as_float(vv.z & 0xffff0000u), hp[5]);
        hp[6] = fmaf(ww, __uint_as_float(vv.w << 16), hp[6]);
        hp[7] = fmaf(ww, __uint_as_float(vv.w & 0xffff0000u), hp[7]);
      }
    }
    m = new_m;
  }
#pragma unroll
  for (int i = 0; i < 8; ++i) {
    hp[i] += __shfl_xor(hp[i], 16);
    hp[i] += __shfl_xor(hp[i], 32);
  }
  if (grp == 0) {
    float denom = (sumex > 0.f) ? sumex : 1.f;
    float inv = 1.f / denom;
    float4* o4 = (float4*)(out + (size_t)node * NDIM);
    o4[gl * 2] = make_float4(hp[0] * inv, hp[1] * inv, hp[2] * inv, hp[3] * inv);
    o4[gl * 2 + 1] = make_float4(hp[4] * inv, hp[5] * inv, hp[6] * inv, hp[7] * inv);
  }
}

extern "C" void kernel_launch(void* const* d_in, const int* in_sizes, int n_in,
                              void* d_out, int out_size, void* d_ws, size_t ws_size,
                              hipStream_t stream) {
  const float* z  = (const float*)d_in[0];
  const float* Wq = (const float*)d_in[1];
  const float* bq = (const float*)d_in[2];
  const float* Wk = (const float*)d_in[3];
  const float* bk = (const float*)d_in[4];
  const float* Wv = (const float*)d_in[5];
  const float* bv = (const float*)d_in[6];
  const int* src  = (const int*)d_in[7];
  const int* dst  = (const int*)d_in[8];
  int n  = in_sizes[0] / NDIM;  // 50000
  int ne = in_sizes[7];         // 800000
  float* out = (float*)d_out;

  char* ws = (char*)d_ws;
  size_t szf32 = (size_t)n * NDIM * sizeof(float);               // 25.6 MB
  size_t szbf  = (size_t)n * NDIM * sizeof(ushort);              // 12.8 MB
  size_t nb = (((size_t)n * sizeof(int)) + 255) & ~(size_t)255;  // 200 KB
  size_t off = 0;
  float* q   = (float*)(ws + off);  off += szf32;
  ushort* kb = (ushort*)(ws + off); off += szbf;
  ushort* vb = (ushort*)(ws + off); off += szbf;
  ushort* zb = (ushort*)(ws + off); off += szbf;
  ushort* wt = (ushort*)(ws + off); off += ((size_t)3 * NDIM * NDIM * 2 + 255) & ~(size_t)255;
  int* counts     = (int*)(ws + off); off += nb;
  int* cursor     = (int*)(ws + off); off += nb;  // reused as bsums
  int* offsets    = (int*)(ws + off); off += nb;
  int* sorted_src = (int*)(ws + off);

  int nblk = (n + 255) / 256;  // 196 (<=256 required by scan_tops)
  size_t zt = (size_t)n * NDIM;

  // 1) bf16 prep
  zconv_kernel<<<(int)((zt / 8 + 255) / 256), 256, 0, stream>>>(z, zb, zt);
  wprep_kernel<<<(3 * NDIM * NDIM + 255) / 256, 256, 0, stream>>>(Wq, Wk, Wv, wt);
  // 2) projections via MFMA
  qkv_mfma<<<(n + 63) / 64, 256, 0, stream>>>(zb, wt, bq, bk, bv, q, kb, vb, n);
  // 3) zero degree counters
  hipMemsetAsync(counts, 0, nb, stream);
  // 4) degree histogram
  hist_kernel<<<(ne + 255) / 256, 256, 0, stream>>>(dst, counts, ne);
  // 5) multi-block exclusive scan (bsums overlaid on cursor)
  scan_blocks<<<nblk, 256, 0, stream>>>(counts, offsets, cursor, n);
  scan_tops<<<1, 256, 0, stream>>>(cursor, nblk);
  scan_add<<<nblk, 256, 0, stream>>>(offsets, cursor, n);
  // 6) re-zero cursor, counting-sort scatter
  hipMemsetAsync(cursor, 0, nb, stream);
  scatter_kernel<<<(ne + 255) / 256, 256, 0, stream>>>(src, dst, offsets, cursor,
                                                       sorted_src, ne);
  // 7) per-node softmax-aggregate
  agg_kernel<<<(n + 3) / 4, 256, 0, stream>>>(q, kb, vb, offsets, counts, sorted_src,
                                              out, n);
}